// Round 1
// baseline (618.189 us; speedup 1.0000x reference)
//
#include <hip/hip_runtime.h>
#include <math.h>

#define B_    64
#define QLEN  32
#define DLEN  2048
#define WORD  300
#define ENT   128
#define AD    256
#define NK    11
#define KDIM  428   // WORD + ENT
#define XPAD  432   // LDS row stride for staged inputs

static __device__ const float d_mus[NK] =
    {-0.9f,-0.7f,-0.5f,-0.3f,-0.1f,0.1f,0.3f,0.5f,0.7f,0.9f,1.0f};
// -0.5 / sigma^2 : sigma=0.1 -> -50 ; sigma=0.001 -> -500000
static __device__ const float d_coef[NK] =
    {-50.f,-50.f,-50.f,-50.f,-50.f,-50.f,-50.f,-50.f,-50.f,-50.f,-500000.f};

// ---------------------------------------------------------------------------
// Kernel Q: q = relu(emb[qtok+1]@W_t + qent@W_e + b), normalize rows,
// zero padded rows, write qhat[B*QLEN, 256].
// 64 blocks x 256 threads, 32 rows/block. Thread: 8 rows x 4 cols.
// ---------------------------------------------------------------------------
__global__ __launch_bounds__(256) void knrm_qtrans(
    const int* __restrict__ qtok,
    const float* __restrict__ qent,
    const float* __restrict__ emb,
    const float* __restrict__ Wt, const float* __restrict__ bt,
    const float* __restrict__ We, const float* __restrict__ be,
    float* __restrict__ qhat)
{
    __shared__ float Xs[32 * XPAD];
    const int tid  = threadIdx.x;
    const int row0 = blockIdx.x * 32;

    for (int r = 0; r < 32; ++r) {
        const int row = row0 + r;
        const int tok = qtok[row] + 1;
        const float* __restrict__ er = emb + (size_t)tok * WORD;
        const float* __restrict__ xr = qent + (size_t)row * ENT;
        for (int c = tid; c < KDIM; c += 256)
            Xs[r * XPAD + c] = (c < WORD) ? er[c] : xr[c - WORD];
    }
    __syncthreads();

    const int rg   = tid >> 6;      // wave id: rows rg*8 .. rg*8+7
    const int cg   = tid & 63;      // cols cg*4 .. cg*4+3
    const int col0 = cg * 4;

    float acc[8][4];
    #pragma unroll
    for (int j = 0; j < 8; ++j)
        acc[j][0] = acc[j][1] = acc[j][2] = acc[j][3] = 0.f;

    for (int i = 0; i < WORD; i += 4) {
        float4 xv[8];
        #pragma unroll
        for (int j = 0; j < 8; ++j)
            xv[j] = *(const float4*)(&Xs[(rg * 8 + j) * XPAD + i]);
        #pragma unroll
        for (int s = 0; s < 4; ++s) {
            const float4 w = *(const float4*)(Wt + (size_t)(i + s) * AD + col0);
            #pragma unroll
            for (int j = 0; j < 8; ++j) {
                const float x = reinterpret_cast<const float*>(&xv[j])[s];
                acc[j][0] = fmaf(x, w.x, acc[j][0]);
                acc[j][1] = fmaf(x, w.y, acc[j][1]);
                acc[j][2] = fmaf(x, w.z, acc[j][2]);
                acc[j][3] = fmaf(x, w.w, acc[j][3]);
            }
        }
    }
    for (int i = 0; i < ENT; i += 4) {
        float4 xv[8];
        #pragma unroll
        for (int j = 0; j < 8; ++j)
            xv[j] = *(const float4*)(&Xs[(rg * 8 + j) * XPAD + WORD + i]);
        #pragma unroll
        for (int s = 0; s < 4; ++s) {
            const float4 w = *(const float4*)(We + (size_t)(i + s) * AD + col0);
            #pragma unroll
            for (int j = 0; j < 8; ++j) {
                const float x = reinterpret_cast<const float*>(&xv[j])[s];
                acc[j][0] = fmaf(x, w.x, acc[j][0]);
                acc[j][1] = fmaf(x, w.y, acc[j][1]);
                acc[j][2] = fmaf(x, w.z, acc[j][2]);
                acc[j][3] = fmaf(x, w.w, acc[j][3]);
            }
        }
    }

    const float4 bt4 = *(const float4*)(bt + col0);
    const float4 be4 = *(const float4*)(be + col0);
    const float bias[4] = {bt4.x + be4.x, bt4.y + be4.y,
                           bt4.z + be4.z, bt4.w + be4.w};
    float ssq[8];
    #pragma unroll
    for (int j = 0; j < 8; ++j) {
        float s = 0.f;
        #pragma unroll
        for (int c = 0; c < 4; ++c) {
            const float v = fmaxf(acc[j][c] + bias[c], 0.f);
            acc[j][c] = v;
            s = fmaf(v, v, s);
        }
        ssq[j] = s;
    }
    #pragma unroll
    for (int m = 32; m; m >>= 1) {
        #pragma unroll
        for (int j = 0; j < 8; ++j)
            ssq[j] += __shfl_xor(ssq[j], m, 64);
    }
    #pragma unroll
    for (int j = 0; j < 8; ++j) {
        const int row = row0 + rg * 8 + j;
        const float rn = (qtok[row] == -1) ? 0.f
                                           : 1.f / (sqrtf(ssq[j]) + 1e-9f);
        float4 o;
        o.x = acc[j][0] * rn; o.y = acc[j][1] * rn;
        o.z = acc[j][2] * rn; o.w = acc[j][3] * rn;
        *(float4*)(qhat + (size_t)row * AD + col0) = o;
    }
}

// ---------------------------------------------------------------------------
// Kernel D: fused doc transform + cosine sim + RBF partial sums.
// grid (DLEN/32, B), 256 threads. 32 doc rows per block.
// ---------------------------------------------------------------------------
__global__ __launch_bounds__(256) void knrm_doc(
    const int* __restrict__ dtok,
    const float* __restrict__ dent,
    const float* __restrict__ emb,
    const float* __restrict__ Wt, const float* __restrict__ bt,
    const float* __restrict__ We, const float* __restrict__ be,
    const float* __restrict__ qhat,
    float* __restrict__ ksum,    // [B, NK, QLEN]
    float* __restrict__ simsum)  // [B, QLEN]
{
    __shared__ float smem[2 * 32 * 260];   // 16640 floats (66.5 KB)
    __shared__ float dn[32];
    float* Xs = smem;                      // 32*432 = 13824 floats (phase 1)
    float* T  = smem;                      // 32*260 (phase 2, overlays Xs)
    float* Qs = smem + 32 * 260;           // 32*260

    const int tid = threadIdx.x;
    const int b   = blockIdx.y;
    const int d0  = blockIdx.x * 32;

    // ---- stage inputs ----
    for (int r = 0; r < 32; ++r) {
        const int drow = b * DLEN + d0 + r;
        const int tok  = dtok[drow] + 1;
        const float* __restrict__ er = emb + (size_t)tok * WORD;
        const float* __restrict__ xr = dent + (size_t)drow * ENT;
        for (int c = tid; c < KDIM; c += 256)
            Xs[r * XPAD + c] = (c < WORD) ? er[c] : xr[c - WORD];
    }
    __syncthreads();

    // ---- transform GEMM: thread = 8 rows x 4 cols ----
    const int rg   = tid >> 6;
    const int cg   = tid & 63;
    const int col0 = cg * 4;

    float acc[8][4];
    #pragma unroll
    for (int j = 0; j < 8; ++j)
        acc[j][0] = acc[j][1] = acc[j][2] = acc[j][3] = 0.f;

    for (int i = 0; i < WORD; i += 4) {
        float4 xv[8];
        #pragma unroll
        for (int j = 0; j < 8; ++j)
            xv[j] = *(const float4*)(&Xs[(rg * 8 + j) * XPAD + i]);
        #pragma unroll
        for (int s = 0; s < 4; ++s) {
            const float4 w = *(const float4*)(Wt + (size_t)(i + s) * AD + col0);
            #pragma unroll
            for (int j = 0; j < 8; ++j) {
                const float x = reinterpret_cast<const float*>(&xv[j])[s];
                acc[j][0] = fmaf(x, w.x, acc[j][0]);
                acc[j][1] = fmaf(x, w.y, acc[j][1]);
                acc[j][2] = fmaf(x, w.z, acc[j][2]);
                acc[j][3] = fmaf(x, w.w, acc[j][3]);
            }
        }
    }
    for (int i = 0; i < ENT; i += 4) {
        float4 xv[8];
        #pragma unroll
        for (int j = 0; j < 8; ++j)
            xv[j] = *(const float4*)(&Xs[(rg * 8 + j) * XPAD + WORD + i]);
        #pragma unroll
        for (int s = 0; s < 4; ++s) {
            const float4 w = *(const float4*)(We + (size_t)(i + s) * AD + col0);
            #pragma unroll
            for (int j = 0; j < 8; ++j) {
                const float x = reinterpret_cast<const float*>(&xv[j])[s];
                acc[j][0] = fmaf(x, w.x, acc[j][0]);
                acc[j][1] = fmaf(x, w.y, acc[j][1]);
                acc[j][2] = fmaf(x, w.z, acc[j][2]);
                acc[j][3] = fmaf(x, w.w, acc[j][3]);
            }
        }
    }

    const float4 bt4 = *(const float4*)(bt + col0);
    const float4 be4 = *(const float4*)(be + col0);
    const float bias[4] = {bt4.x + be4.x, bt4.y + be4.y,
                           bt4.z + be4.z, bt4.w + be4.w};
    float ssq[8];
    #pragma unroll
    for (int j = 0; j < 8; ++j) {
        float s = 0.f;
        #pragma unroll
        for (int c = 0; c < 4; ++c) {
            const float v = fmaxf(acc[j][c] + bias[c], 0.f);
            acc[j][c] = v;
            s = fmaf(v, v, s);
        }
        ssq[j] = s;
    }
    #pragma unroll
    for (int m = 32; m; m >>= 1) {
        #pragma unroll
        for (int j = 0; j < 8; ++j)
            ssq[j] += __shfl_xor(ssq[j], m, 64);
    }

    __syncthreads();   // everyone done reading Xs; safe to overlay T/Qs

    // write T (unnormalized, relu'd) and per-row inverse norms
    #pragma unroll
    for (int j = 0; j < 8; ++j) {
        const int r = rg * 8 + j;
        float4 o;
        o.x = acc[j][0]; o.y = acc[j][1]; o.z = acc[j][2]; o.w = acc[j][3];
        *(float4*)(&T[r * 260 + col0]) = o;
        if (cg == 0) {
            const int tok = dtok[b * DLEN + d0 + r];
            dn[r] = (tok == -1) ? 0.f : 1.f / (sqrtf(ssq[j]) + 1e-9f);
        }
    }
    // stage qhat for this batch
    for (int idx = tid; idx < 32 * 64; idx += 256) {
        const int q  = idx >> 6;
        const int c4 = (idx & 63) * 4;
        *(float4*)(&Qs[q * 260 + c4]) =
            *(const float4*)(qhat + ((size_t)(b * QLEN + q)) * AD + c4);
    }
    __syncthreads();

    // ---- sims: thread = 1 q x 4 d ----
    const int q  = tid >> 3;
    const int ds = tid & 7;
    float sims[4] = {0.f, 0.f, 0.f, 0.f};
    for (int k4 = 0; k4 < AD; k4 += 4) {
        const float4 qv = *(const float4*)(&Qs[q * 260 + k4]);
        #pragma unroll
        for (int dd = 0; dd < 4; ++dd) {
            const float4 tv = *(const float4*)(&T[(ds + 8 * dd) * 260 + k4]);
            sims[dd] += qv.x * tv.x + qv.y * tv.y + qv.z * tv.z + qv.w * tv.w;
        }
    }

    // ---- RBF bank + reductions ----
    float kp[NK];
    #pragma unroll
    for (int k = 0; k < NK; ++k) kp[k] = 0.f;
    float ssum = 0.f;
    #pragma unroll
    for (int dd = 0; dd < 4; ++dd) {
        const float s = sims[dd] * dn[ds + 8 * dd];
        ssum += s;
        #pragma unroll
        for (int k = 0; k < NK; ++k) {
            const float t = s - d_mus[k];
            kp[k] += __expf(d_coef[k] * t * t);
        }
    }
    #pragma unroll
    for (int m = 4; m; m >>= 1) {
        ssum += __shfl_xor(ssum, m, 8);
        #pragma unroll
        for (int k = 0; k < NK; ++k) kp[k] += __shfl_xor(kp[k], m, 8);
    }
    if (ds == 0) {
        #pragma unroll
        for (int k = 0; k < NK; ++k)
            atomicAdd(&ksum[((size_t)b * NK + k) * QLEN + q], kp[k]);
        atomicAdd(&simsum[b * QLEN + q], ssum);
    }
}

// ---------------------------------------------------------------------------
// Kernel F: masked log, reduce over q, dot with W_c.
// ---------------------------------------------------------------------------
__global__ __launch_bounds__(384) void knrm_final(
    const float* __restrict__ ksum,
    const float* __restrict__ simsum,
    const float* __restrict__ Wc, const float* __restrict__ bc,
    float* __restrict__ out)
{
    __shared__ float red[NK][QLEN];
    __shared__ float res[NK];
    const int b = blockIdx.x;
    const int t = threadIdx.x;
    if (t < NK * QLEN) {
        const int k = t >> 5;
        const int q = t & 31;
        const float ms = simsum[b * QLEN + q];
        red[k][q] = (ms != 0.0f)
            ? logf(ksum[((size_t)b * NK + k) * QLEN + q] + 1e-6f)
            : 0.0f;
    }
    __syncthreads();
    if (t < NK) {
        float s = 0.f;
        for (int q = 0; q < QLEN; ++q) s += red[t][q];
        res[t] = s;
    }
    __syncthreads();
    if (t == 0) {
        float s = bc[0];
        for (int k = 0; k < NK; ++k) s += res[k] * Wc[k];
        out[b] = s;
    }
}

// ---------------------------------------------------------------------------
extern "C" void kernel_launch(void* const* d_in, const int* in_sizes, int n_in,
                              void* d_out, int out_size, void* d_ws, size_t ws_size,
                              hipStream_t stream)
{
    (void)in_sizes; (void)n_in; (void)out_size; (void)ws_size;
    const int*   qtok = (const int*)d_in[0];
    const int*   dtok = (const int*)d_in[1];
    const float* qent = (const float*)d_in[2];
    const float* dent = (const float*)d_in[3];
    const float* emb  = (const float*)d_in[4];
    const float* Wt   = (const float*)d_in[5];
    const float* bt   = (const float*)d_in[6];
    const float* We   = (const float*)d_in[7];
    const float* be   = (const float*)d_in[8];
    const float* Wc   = (const float*)d_in[9];
    const float* bc   = (const float*)d_in[10];
    float* out = (float*)d_out;

    char* ws = (char*)d_ws;
    float* qhat   = (float*)ws;                                    // B*QLEN*AD
    float* ksum   = (float*)(ws + (size_t)B_ * QLEN * AD * 4);     // B*NK*QLEN
    float* simsum = ksum + (size_t)B_ * NK * QLEN;                 // B*QLEN

    hipMemsetAsync(ksum, 0,
                   ((size_t)B_ * NK * QLEN + (size_t)B_ * QLEN) * sizeof(float),
                   stream);

    knrm_qtrans<<<dim3((B_ * QLEN) / 32), dim3(256), 0, stream>>>(
        qtok, qent, emb, Wt, bt, We, be, qhat);

    knrm_doc<<<dim3(DLEN / 32, B_), dim3(256), 0, stream>>>(
        dtok, dent, emb, Wt, bt, We, be, qhat, ksum, simsum);

    knrm_final<<<dim3(B_), dim3(384), 0, stream>>>(ksum, simsum, Wc, bc, out);
}

// Round 2
// 322.544 us; speedup vs baseline: 1.9166x; 1.9166x over previous
//
#include <hip/hip_runtime.h>
#include <math.h>

#define B_    64
#define QLEN  32
#define DLEN  2048
#define WORD  300
#define ENT   128
#define AD    256
#define NK    11
#define KDIM  428
#define KPAD  448          // 14 K-steps of 32
#define KSTEPS 14

typedef __bf16 bf16x8 __attribute__((ext_vector_type(8)));
typedef __bf16 bf16x4 __attribute__((ext_vector_type(4)));
typedef float  f32x4  __attribute__((ext_vector_type(4)));

static __device__ const float d_mus[NK] =
    {-0.9f,-0.7f,-0.5f,-0.3f,-0.1f,0.1f,0.3f,0.5f,0.7f,0.9f,1.0f};
static __device__ const float d_coef[NK] =
    {-50.f,-50.f,-50.f,-50.f,-50.f,-50.f,-50.f,-50.f,-50.f,-50.f,-500000.f};

// ---------------------------------------------------------------------------
// W-pack: Wp bf16 in B-fragment order. tile(s,nb) = 64 lanes x 16B.
// lane l, j: B[k = s*32 + (l>>4)*8 + j][col = nb*16 + (l&15)]
// Also bias[col] = bt+be.
// ---------------------------------------------------------------------------
__global__ __launch_bounds__(256) void knrm_wpack(
    const float* __restrict__ Wt, const float* __restrict__ We,
    const float* __restrict__ bt, const float* __restrict__ be,
    __bf16* __restrict__ Wp, float* __restrict__ bias)
{
    const int idx = blockIdx.x * 256 + threadIdx.x;   // 0..14335
    if (idx < AD) bias[idx] = bt[idx] + be[idx];
    const int tile = idx >> 6, l = idx & 63;
    const int s  = tile >> 4, nb = tile & 15;
    const int col = nb * 16 + (l & 15);
    const int k0  = s * 32 + (l >> 4) * 8;
    bf16x8 h;
    #pragma unroll
    for (int j = 0; j < 8; ++j) {
        const int k = k0 + j;
        float v = 0.f;
        if (k < WORD)      v = Wt[(size_t)k * AD + col];
        else if (k < KDIM) v = We[(size_t)(k - WORD) * AD + col];
        h[j] = (__bf16)v;
    }
    *(bf16x8*)((char*)Wp + (size_t)idx * 16) = h;
}

// ---------------------------------------------------------------------------
// Kernel Q: fp32 transform of query rows; writes qhat bf16, XOR-swizzled
// row layout [32][256] per batch: byte = (q*512 + col*2) ^ ((q&7)<<4).
// ---------------------------------------------------------------------------
#define XPAD 432
__global__ __launch_bounds__(256) void knrm_qtrans(
    const int* __restrict__ qtok,
    const float* __restrict__ qent,
    const float* __restrict__ emb,
    const float* __restrict__ Wt, const float* __restrict__ bt,
    const float* __restrict__ We, const float* __restrict__ be,
    char* __restrict__ qhatb)
{
    __shared__ float Xs[32 * XPAD];
    const int tid  = threadIdx.x;
    const int row0 = blockIdx.x * 32;

    for (int r = 0; r < 32; ++r) {
        const int row = row0 + r;
        const int tok = qtok[row] + 1;
        const float* __restrict__ er = emb + (size_t)tok * WORD;
        const float* __restrict__ xr = qent + (size_t)row * ENT;
        for (int c = tid; c < KDIM; c += 256)
            Xs[r * XPAD + c] = (c < WORD) ? er[c] : xr[c - WORD];
    }
    __syncthreads();

    const int rg   = tid >> 6;
    const int cg   = tid & 63;
    const int col0 = cg * 4;

    float acc[8][4];
    #pragma unroll
    for (int j = 0; j < 8; ++j)
        acc[j][0] = acc[j][1] = acc[j][2] = acc[j][3] = 0.f;

    for (int i = 0; i < KDIM; i += 4) {
        const float* __restrict__ Wbase =
            (i < WORD) ? (Wt + (size_t)i * AD) : (We + (size_t)(i - WORD) * AD);
        float4 xv[8];
        #pragma unroll
        for (int j = 0; j < 8; ++j)
            xv[j] = *(const float4*)(&Xs[(rg * 8 + j) * XPAD + i]);
        #pragma unroll
        for (int s = 0; s < 4; ++s) {
            const float4 w = *(const float4*)(Wbase + (size_t)s * AD + col0);
            #pragma unroll
            for (int j = 0; j < 8; ++j) {
                const float x = reinterpret_cast<const float*>(&xv[j])[s];
                acc[j][0] = fmaf(x, w.x, acc[j][0]);
                acc[j][1] = fmaf(x, w.y, acc[j][1]);
                acc[j][2] = fmaf(x, w.z, acc[j][2]);
                acc[j][3] = fmaf(x, w.w, acc[j][3]);
            }
        }
    }

    const float4 bt4 = *(const float4*)(bt + col0);
    const float4 be4 = *(const float4*)(be + col0);
    const float bias[4] = {bt4.x + be4.x, bt4.y + be4.y,
                           bt4.z + be4.z, bt4.w + be4.w};
    float ssq[8];
    #pragma unroll
    for (int j = 0; j < 8; ++j) {
        float s = 0.f;
        #pragma unroll
        for (int c = 0; c < 4; ++c) {
            const float v = fmaxf(acc[j][c] + bias[c], 0.f);
            acc[j][c] = v;
            s = fmaf(v, v, s);
        }
        ssq[j] = s;
    }
    #pragma unroll
    for (int m = 32; m; m >>= 1) {
        #pragma unroll
        for (int j = 0; j < 8; ++j)
            ssq[j] += __shfl_xor(ssq[j], m, 64);
    }
    char* qb = qhatb + (size_t)blockIdx.x * (QLEN * AD * 2);
    #pragma unroll
    for (int j = 0; j < 8; ++j) {
        const int q   = rg * 8 + j;
        const int row = row0 + q;
        const float rn = (qtok[row] == -1) ? 0.f
                                           : 1.f / (sqrtf(ssq[j]) + 1e-9f);
        bf16x4 h;
        #pragma unroll
        for (int c = 0; c < 4; ++c) h[c] = (__bf16)(acc[j][c] * rn);
        const int byte = (q * 512 + col0 * 2) ^ ((q & 7) << 4);
        *(bf16x4*)(qb + byte) = h;
    }
}

// ---------------------------------------------------------------------------
// Kernel D: fused bf16-MFMA doc transform + sims + RBF. 64 docs/block.
// ---------------------------------------------------------------------------
__global__ __launch_bounds__(256) void knrm_doc(
    const int* __restrict__ dtok,
    const float* __restrict__ dent,
    const float* __restrict__ emb,
    const __bf16* __restrict__ Wp,
    const float* __restrict__ bias,
    const char* __restrict__ qhatb,
    float* __restrict__ ksum,    // [B, NK, QLEN]
    float* __restrict__ simsum)  // [B, QLEN]
{
    __shared__ __align__(16) char sm[75776];
    char*  Xb  = sm;                              // X [64][448] bf16 swz; later T [64][256]
    char*  Qb  = sm + 57344;                      // Qs [32][256] bf16 swz
    float* red = (float*)(sm + 57344 + 16384);    // [12][32]
    float* ssq = red + 12 * 32;                   // [64]
    float* dn  = ssq + 64;                        // [64]

    const int tid = threadIdx.x;
    const int b   = blockIdx.y;
    const int d0  = blockIdx.x * 64;

    // zero red + ssq (contiguous 448 floats)
    for (int i = tid; i < 448; i += 256) red[i] = 0.f;

    // stage Qs (already swizzled in global)
    {
        const char* src = qhatb + (size_t)b * (QLEN * AD * 2);
        for (int i = tid * 16; i < QLEN * AD * 2; i += 256 * 16)
            *(f32x4*)(Qb + i) = *(const f32x4*)(src + i);
    }
    // stage X: 64 rows x 428 f32 -> bf16 swizzled; 107 float4 per row
    for (int i = tid; i < 64 * 107; i += 256) {
        const int r  = i / 107;
        const int c4 = (i - r * 107) * 4;
        const int drow = b * DLEN + d0 + r;
        f32x4 v;
        if (c4 < WORD) {
            const int tok = dtok[drow] + 1;
            v = *(const f32x4*)(emb + (size_t)tok * WORD + c4);
        } else {
            v = *(const f32x4*)(dent + (size_t)drow * ENT + (c4 - WORD));
        }
        bf16x4 h;
        #pragma unroll
        for (int c = 0; c < 4; ++c) h[c] = (__bf16)v[c];
        const int byte = (r * 896 + c4 * 2) ^ ((r & 7) << 4);
        *(bf16x4*)(Xb + byte) = h;
    }
    // zero-pad cols 428..447
    for (int i = tid; i < 64 * 5; i += 256) {
        const int r  = i / 5;
        const int c4 = KDIM + (i - r * 5) * 4;
        const int byte = (r * 896 + c4 * 2) ^ ((r & 7) << 4);
        bf16x4 z = {};
        *(bf16x4*)(Xb + byte) = z;
    }
    __syncthreads();

    const int w  = tid >> 6;
    const int l  = tid & 63;
    const int lr = l & 15;
    const int lg = l >> 4;

    // ---- transform MFMA: M=64 docs, N=64 cols (this wave), K=448 ----
    f32x4 acc[4][4];
    #pragma unroll
    for (int mf = 0; mf < 4; ++mf)
        #pragma unroll
        for (int nf = 0; nf < 4; ++nf)
            acc[mf][nf] = (f32x4){0.f, 0.f, 0.f, 0.f};

    for (int s = 0; s < KSTEPS; ++s) {
        bf16x8 a[4];
        #pragma unroll
        for (int mf = 0; mf < 4; ++mf) {
            const int row  = mf * 16 + lr;
            const int byte = (row * 896 + (s * 32 + lg * 8) * 2) ^ ((row & 7) << 4);
            a[mf] = *(const bf16x8*)(Xb + byte);
        }
        bf16x8 bf[4];
        #pragma unroll
        for (int nf = 0; nf < 4; ++nf) {
            const int tile = s * 16 + w * 4 + nf;
            bf[nf] = *(const bf16x8*)((const char*)Wp + (size_t)tile * 1024 + l * 16);
        }
        #pragma unroll
        for (int mf = 0; mf < 4; ++mf)
            #pragma unroll
            for (int nf = 0; nf < 4; ++nf)
                acc[mf][nf] = __builtin_amdgcn_mfma_f32_16x16x32_bf16(
                    a[mf], bf[nf], acc[mf][nf], 0, 0, 0);
    }

    // bias + relu + row square-sums
    float bv[4];
    #pragma unroll
    for (int nf = 0; nf < 4; ++nf) bv[nf] = bias[w * 64 + nf * 16 + lr];
    float sq[4][4];
    #pragma unroll
    for (int mf = 0; mf < 4; ++mf)
        #pragma unroll
        for (int reg = 0; reg < 4; ++reg) {
            float s = 0.f;
            #pragma unroll
            for (int nf = 0; nf < 4; ++nf) {
                const float v = fmaxf(acc[mf][nf][reg] + bv[nf], 0.f);
                acc[mf][nf][reg] = v;
                s = fmaf(v, v, s);
            }
            sq[mf][reg] = s;
        }
    #pragma unroll
    for (int m = 1; m <= 8; m <<= 1)
        #pragma unroll
        for (int mf = 0; mf < 4; ++mf)
            #pragma unroll
            for (int reg = 0; reg < 4; ++reg)
                sq[mf][reg] += __shfl_xor(sq[mf][reg], m, 64);
    if (lr == 0) {
        #pragma unroll
        for (int mf = 0; mf < 4; ++mf)
            #pragma unroll
            for (int reg = 0; reg < 4; ++reg)
                atomicAdd(&ssq[mf * 16 + lg * 4 + reg], sq[mf][reg]);
    }
    __syncthreads();   // X reads done; ssq complete

    // write T bf16 swizzled over Xb: T[doc][col], byte=(doc*512+col*2)^((doc&7)<<4)
    #pragma unroll
    for (int mf = 0; mf < 4; ++mf)
        #pragma unroll
        for (int nf = 0; nf < 4; ++nf)
            #pragma unroll
            for (int reg = 0; reg < 4; ++reg) {
                const int doc = mf * 16 + lg * 4 + reg;
                const int col = w * 64 + nf * 16 + lr;
                const int byte = (doc * 512 + col * 2) ^ ((doc & 7) << 4);
                *(__bf16*)(Xb + byte) = (__bf16)acc[mf][nf][reg];
            }
    if (tid < 64) {
        const int tok = dtok[b * DLEN + d0 + tid];
        dn[tid] = (tok == -1) ? 0.f : 1.f / (sqrtf(ssq[tid]) + 1e-9f);
    }
    __syncthreads();

    // ---- sims MFMA: M=32 q, N=16 docs (this wave), K=256 ----
    f32x4 sacc[2];
    sacc[0] = (f32x4){0.f,0.f,0.f,0.f};
    sacc[1] = (f32x4){0.f,0.f,0.f,0.f};
    const int doc_l = w * 16 + lr;
    for (int s = 0; s < 8; ++s) {
        bf16x8 qa[2];
        #pragma unroll
        for (int mf = 0; mf < 2; ++mf) {
            const int q = mf * 16 + lr;
            const int byte = (q * 512 + (s * 32 + lg * 8) * 2) ^ ((q & 7) << 4);
            qa[mf] = *(const bf16x8*)(Qb + byte);
        }
        const int tbyte = (doc_l * 512 + (s * 32 + lg * 8) * 2) ^ ((doc_l & 7) << 4);
        const bf16x8 tb = *(const bf16x8*)(Xb + tbyte);
        #pragma unroll
        for (int mf = 0; mf < 2; ++mf)
            sacc[mf] = __builtin_amdgcn_mfma_f32_16x16x32_bf16(
                qa[mf], tb, sacc[mf], 0, 0, 0);
    }

    // ---- RBF + reductions ----
    const float dnv = dn[doc_l];
    float kq[2][4][12];
    #pragma unroll
    for (int mf = 0; mf < 2; ++mf)
        #pragma unroll
        for (int reg = 0; reg < 4; ++reg) {
            const float sv = sacc[mf][reg] * dnv;
            kq[mf][reg][11] = sv;
            #pragma unroll
            for (int k = 0; k < NK; ++k) {
                const float t = sv - d_mus[k];
                kq[mf][reg][k] = __expf(d_coef[k] * t * t);
            }
        }
    #pragma unroll
    for (int m = 1; m <= 8; m <<= 1)
        #pragma unroll
        for (int mf = 0; mf < 2; ++mf)
            #pragma unroll
            for (int reg = 0; reg < 4; ++reg)
                #pragma unroll
                for (int k = 0; k < 12; ++k)
                    kq[mf][reg][k] += __shfl_xor(kq[mf][reg][k], m, 64);
    if (lr == 0) {
        #pragma unroll
        for (int mf = 0; mf < 2; ++mf)
            #pragma unroll
            for (int reg = 0; reg < 4; ++reg) {
                const int q = mf * 16 + lg * 4 + reg;
                #pragma unroll
                for (int k = 0; k < 12; ++k)
                    atomicAdd(&red[k * 32 + q], kq[mf][reg][k]);
            }
    }
    __syncthreads();

    for (int i = tid; i < 384; i += 256) {
        const int k = i >> 5, q = i & 31;
        if (k < NK)      atomicAdd(&ksum[((size_t)b * NK + k) * QLEN + q], red[i]);
        else             atomicAdd(&simsum[b * QLEN + q], red[i]);
    }
}

// ---------------------------------------------------------------------------
__global__ __launch_bounds__(384) void knrm_final(
    const float* __restrict__ ksum,
    const float* __restrict__ simsum,
    const float* __restrict__ Wc, const float* __restrict__ bc,
    float* __restrict__ out)
{
    __shared__ float redq[NK][QLEN];
    __shared__ float res[NK];
    const int b = blockIdx.x;
    const int t = threadIdx.x;
    if (t < NK * QLEN) {
        const int k = t >> 5;
        const int q = t & 31;
        const float ms = simsum[b * QLEN + q];
        redq[k][q] = (ms != 0.0f)
            ? logf(ksum[((size_t)b * NK + k) * QLEN + q] + 1e-6f)
            : 0.0f;
    }
    __syncthreads();
    if (t < NK) {
        float s = 0.f;
        for (int q = 0; q < QLEN; ++q) s += redq[t][q];
        res[t] = s;
    }
    __syncthreads();
    if (t == 0) {
        float s = bc[0];
        for (int k = 0; k < NK; ++k) s += res[k] * Wc[k];
        out[b] = s;
    }
}

// ---------------------------------------------------------------------------
extern "C" void kernel_launch(void* const* d_in, const int* in_sizes, int n_in,
                              void* d_out, int out_size, void* d_ws, size_t ws_size,
                              hipStream_t stream)
{
    (void)in_sizes; (void)n_in; (void)out_size; (void)ws_size;
    const int*   qtok = (const int*)d_in[0];
    const int*   dtok = (const int*)d_in[1];
    const float* qent = (const float*)d_in[2];
    const float* dent = (const float*)d_in[3];
    const float* emb  = (const float*)d_in[4];
    const float* Wt   = (const float*)d_in[5];
    const float* bt   = (const float*)d_in[6];
    const float* We   = (const float*)d_in[7];
    const float* be   = (const float*)d_in[8];
    const float* Wc   = (const float*)d_in[9];
    const float* bc   = (const float*)d_in[10];
    float* out = (float*)d_out;

    char* ws = (char*)d_ws;
    char*   qhatb = ws;                                   // 1 MB bf16 swz
    __bf16* Wp    = (__bf16*)(ws + 1048576);              // 229376 B
    float*  bias  = (float*)(ws + 1048576 + 229376);      // 1 KB
    float*  ksum  = (float*)(ws + 1048576 + 229376 + 1024);        // 90112 B
    float*  simsum= (float*)(ws + 1048576 + 229376 + 1024 + 90112);// 8192 B

    hipMemsetAsync(ksum, 0, (size_t)(90112 + 8192), stream);

    knrm_wpack<<<dim3(56), dim3(256), 0, stream>>>(Wt, We, bt, be, Wp, bias);
    knrm_qtrans<<<dim3(B_), dim3(256), 0, stream>>>(
        qtok, qent, emb, Wt, bt, We, be, qhatb);
    knrm_doc<<<dim3(DLEN / 64, B_), dim3(256), 0, stream>>>(
        dtok, dent, emb, Wp, bias, qhatb, ksum, simsum);
    knrm_final<<<dim3(B_), dim3(384), 0, stream>>>(ksum, simsum, Wc, bc, out);
}

// Round 3
// 193.768 us; speedup vs baseline: 3.1904x; 1.6646x over previous
//
#include <hip/hip_runtime.h>
#include <math.h>

#define B_    64
#define QLEN  32
#define DLEN  2048
#define WORD  300
#define ENT   128
#define AD    256
#define NK    11
#define KDIM  428
#define KHALF 224
#define KSH   7            // k-steps (of 32) per half

typedef __bf16 bf16x8 __attribute__((ext_vector_type(8)));
typedef __bf16 bf16x4 __attribute__((ext_vector_type(4)));
typedef float  f32x4  __attribute__((ext_vector_type(4)));

static __device__ const float d_mus[NK] =
    {-0.9f,-0.7f,-0.5f,-0.3f,-0.1f,0.1f,0.3f,0.5f,0.7f,0.9f,1.0f};
static __device__ const float d_coef[NK] =
    {-50.f,-50.f,-50.f,-50.f,-50.f,-50.f,-50.f,-50.f,-50.f,-50.f,-500000.f};

// ---------------------------------------------------------------------------
// W-pack: Wp bf16 in B-fragment order. tile(s,nb) = 64 lanes x 16B.
// lane l, j: B[k = s*32 + (l>>4)*8 + j][col = nb*16 + (l&15)]
// ---------------------------------------------------------------------------
__global__ __launch_bounds__(256) void knrm_wpack(
    const float* __restrict__ Wt, const float* __restrict__ We,
    const float* __restrict__ bt, const float* __restrict__ be,
    __bf16* __restrict__ Wp, float* __restrict__ bias)
{
    const int idx = blockIdx.x * 256 + threadIdx.x;   // 0..14335
    if (idx < AD) bias[idx] = bt[idx] + be[idx];
    const int tile = idx >> 6, l = idx & 63;
    const int s  = tile >> 4, nb = tile & 15;
    const int col = nb * 16 + (l & 15);
    const int k0  = s * 32 + (l >> 4) * 8;
    bf16x8 h;
    #pragma unroll
    for (int j = 0; j < 8; ++j) {
        const int k = k0 + j;
        float v = 0.f;
        if (k < WORD)      v = Wt[(size_t)k * AD + col];
        else if (k < KDIM) v = We[(size_t)(k - WORD) * AD + col];
        h[j] = (__bf16)v;
    }
    *(bf16x8*)((char*)Wp + (size_t)idx * 16) = h;
}

// ---------------------------------------------------------------------------
// Kernel Q: fp32 transform of query rows; writes qhat bf16, XOR-swizzled:
// byte = (q*512 + col*2) ^ ((q&7)<<4) within each batch slab of 16 KB.
// ---------------------------------------------------------------------------
#define XPAD 432
__global__ __launch_bounds__(256) void knrm_qtrans(
    const int* __restrict__ qtok,
    const float* __restrict__ qent,
    const float* __restrict__ emb,
    const float* __restrict__ Wt, const float* __restrict__ bt,
    const float* __restrict__ We, const float* __restrict__ be,
    char* __restrict__ qhatb)
{
    __shared__ float Xs[32 * XPAD];
    const int tid  = threadIdx.x;
    const int row0 = blockIdx.x * 32;

    for (int r = 0; r < 32; ++r) {
        const int row = row0 + r;
        const int tok = qtok[row] + 1;
        const float* __restrict__ er = emb + (size_t)tok * WORD;
        const float* __restrict__ xr = qent + (size_t)row * ENT;
        for (int c = tid; c < KDIM; c += 256)
            Xs[r * XPAD + c] = (c < WORD) ? er[c] : xr[c - WORD];
    }
    __syncthreads();

    const int rg   = tid >> 6;
    const int cg   = tid & 63;
    const int col0 = cg * 4;

    float acc[8][4];
    #pragma unroll
    for (int j = 0; j < 8; ++j)
        acc[j][0] = acc[j][1] = acc[j][2] = acc[j][3] = 0.f;

    for (int i = 0; i < KDIM; i += 4) {
        const float* __restrict__ Wbase =
            (i < WORD) ? (Wt + (size_t)i * AD) : (We + (size_t)(i - WORD) * AD);
        float4 xv[8];
        #pragma unroll
        for (int j = 0; j < 8; ++j)
            xv[j] = *(const float4*)(&Xs[(rg * 8 + j) * XPAD + i]);
        #pragma unroll
        for (int s = 0; s < 4; ++s) {
            const float4 w = *(const float4*)(Wbase + (size_t)s * AD + col0);
            #pragma unroll
            for (int j = 0; j < 8; ++j) {
                const float x = reinterpret_cast<const float*>(&xv[j])[s];
                acc[j][0] = fmaf(x, w.x, acc[j][0]);
                acc[j][1] = fmaf(x, w.y, acc[j][1]);
                acc[j][2] = fmaf(x, w.z, acc[j][2]);
                acc[j][3] = fmaf(x, w.w, acc[j][3]);
            }
        }
    }

    const float4 bt4 = *(const float4*)(bt + col0);
    const float4 be4 = *(const float4*)(be + col0);
    const float bias[4] = {bt4.x + be4.x, bt4.y + be4.y,
                           bt4.z + be4.z, bt4.w + be4.w};
    float ssq[8];
    #pragma unroll
    for (int j = 0; j < 8; ++j) {
        float s = 0.f;
        #pragma unroll
        for (int c = 0; c < 4; ++c) {
            const float v = fmaxf(acc[j][c] + bias[c], 0.f);
            acc[j][c] = v;
            s = fmaf(v, v, s);
        }
        ssq[j] = s;
    }
    #pragma unroll
    for (int m = 32; m; m >>= 1) {
        #pragma unroll
        for (int j = 0; j < 8; ++j)
            ssq[j] += __shfl_xor(ssq[j], m, 64);
    }
    char* qb = qhatb + (size_t)blockIdx.x * (QLEN * AD * 2);
    #pragma unroll
    for (int j = 0; j < 8; ++j) {
        const int q   = rg * 8 + j;
        const int row = row0 + q;
        const float rn = (qtok[row] == -1) ? 0.f
                                           : 1.f / (sqrtf(ssq[j]) + 1e-9f);
        bf16x4 h;
        #pragma unroll
        for (int c = 0; c < 4; ++c) h[c] = (__bf16)(acc[j][c] * rn);
        const int byte = (q * 512 + col0 * 2) ^ ((q & 7) << 4);
        *(bf16x4*)(qb + byte) = h;
    }
}

// ---------------------------------------------------------------------------
// Kernel D v3: 512 threads (8 waves), 64 docs/block, K-split X staging,
// Q B-frags from global, swapped sims operands (docs on accumulator rows).
// ---------------------------------------------------------------------------
__global__ __launch_bounds__(512, 6) void knrm_doc(
    const int* __restrict__ dtok,
    const float* __restrict__ dent,
    const float* __restrict__ emb,
    const __bf16* __restrict__ Wp,
    const float* __restrict__ bias,
    const char* __restrict__ qhatb,
    float* __restrict__ ksum,    // [B, NK, QLEN]
    float* __restrict__ simsum)  // [B, QLEN]
{
    __shared__ __align__(16) char sm[32768 + 2048];
    char*  Xb   = sm;                      // X half [64][224] bf16 swz; later T [64][256] bf16 swz
    float* red  = (float*)(sm + 32768);    // [12][32]
    float* ssq  = red + 384;               // [64]
    int*   toks = (int*)(ssq + 64);        // [64] tok+1

    const int tid = threadIdx.x;
    const int b   = blockIdx.y;
    const int d0  = blockIdx.x * 64;
    const int w   = tid >> 6;
    const int l   = tid & 63;
    const int lr  = l & 15;
    const int lg  = l >> 4;
    const int drow0 = b * DLEN + d0;

    for (int i = tid; i < 448; i += 512) red[i] = 0.f;
    if (tid < 64) toks[tid] = dtok[drow0 + tid] + 1;
    __syncthreads();

    f32x4 acc[4][2];
    #pragma unroll
    for (int mf = 0; mf < 4; ++mf)
        #pragma unroll
        for (int nf = 0; nf < 2; ++nf)
            acc[mf][nf] = (f32x4){0.f, 0.f, 0.f, 0.f};

    #pragma unroll
    for (int h = 0; h < 2; ++h) {
        if (h) __syncthreads();            // prior X reads done before overwrite
        // stage half h: [64 rows][56 bf16x4 slots], swizzled
        for (int i = tid; i < 4096; i += 512) {
            const int r = i >> 6, s = i & 63;
            if (s < 56) {
                const int k = h * KHALF + s * 4;
                bf16x4 hv = {};
                if (k < KDIM) {
                    f32x4 v;
                    if (k < WORD)
                        v = *(const f32x4*)(emb + (size_t)toks[r] * WORD + k);
                    else
                        v = *(const f32x4*)(dent + (size_t)(drow0 + r) * ENT + (k - WORD));
                    #pragma unroll
                    for (int c = 0; c < 4; ++c) hv[c] = (__bf16)v[c];
                }
                const int byte = (r * 448 + s * 8) ^ ((r & 7) << 4);
                *(bf16x4*)(Xb + byte) = hv;
            }
        }
        __syncthreads();
        #pragma unroll
        for (int s = 0; s < KSH; ++s) {
            bf16x8 a[4];
            #pragma unroll
            for (int mf = 0; mf < 4; ++mf) {
                const int row  = mf * 16 + lr;
                const int byte = (row * 448 + (s * 32 + lg * 8) * 2) ^ ((row & 7) << 4);
                a[mf] = *(const bf16x8*)(Xb + byte);
            }
            bf16x8 bfv[2];
            #pragma unroll
            for (int nf = 0; nf < 2; ++nf) {
                const int tile = (h * KSH + s) * 16 + (w * 2 + nf);
                bfv[nf] = *(const bf16x8*)((const char*)Wp + (size_t)tile * 1024 + l * 16);
            }
            #pragma unroll
            for (int mf = 0; mf < 4; ++mf)
                #pragma unroll
                for (int nf = 0; nf < 2; ++nf)
                    acc[mf][nf] = __builtin_amdgcn_mfma_f32_16x16x32_bf16(
                        a[mf], bfv[nf], acc[mf][nf], 0, 0, 0);
        }
    }
    __syncthreads();   // all X reads done; Xb reusable as T

    // bias + relu + row square-sums (wave's 32-col slice)
    float bv[2];
    #pragma unroll
    for (int nf = 0; nf < 2; ++nf) bv[nf] = bias[w * 32 + nf * 16 + lr];
    float sq[4][4];
    #pragma unroll
    for (int mf = 0; mf < 4; ++mf)
        #pragma unroll
        for (int reg = 0; reg < 4; ++reg) {
            const float v0 = fmaxf(acc[mf][0][reg] + bv[0], 0.f);
            const float v1 = fmaxf(acc[mf][1][reg] + bv[1], 0.f);
            acc[mf][0][reg] = v0;
            acc[mf][1][reg] = v1;
            sq[mf][reg] = fmaf(v0, v0, v1 * v1);
        }
    #pragma unroll
    for (int m = 1; m <= 8; m <<= 1)
        #pragma unroll
        for (int mf = 0; mf < 4; ++mf)
            #pragma unroll
            for (int reg = 0; reg < 4; ++reg)
                sq[mf][reg] += __shfl_xor(sq[mf][reg], m, 64);
    if (lr == 0) {
        #pragma unroll
        for (int mf = 0; mf < 4; ++mf)
            #pragma unroll
            for (int reg = 0; reg < 4; ++reg)
                atomicAdd(&ssq[mf * 16 + lg * 4 + reg], sq[mf][reg]);
    }
    // write T [doc][256] bf16, byte = (doc*512+col*2)^((doc&7)<<4)
    #pragma unroll
    for (int mf = 0; mf < 4; ++mf)
        #pragma unroll
        for (int nf = 0; nf < 2; ++nf)
            #pragma unroll
            for (int reg = 0; reg < 4; ++reg) {
                const int doc  = mf * 16 + lg * 4 + reg;
                const int col  = w * 32 + nf * 16 + lr;
                const int byte = (doc * 512 + col * 2) ^ ((doc & 7) << 4);
                *(__bf16*)(Xb + byte) = (__bf16)acc[mf][nf][reg];
            }
    __syncthreads();   // T + ssq visible

    // ---- sims: wave w -> dtile = w&3 (16 docs as M), qtile = w>>2 (16 q as N)
    const int dtile = w & 3, qtile = w >> 2;
    const int tdoc  = dtile * 16 + lr;
    const int q     = qtile * 16 + lr;
    const char* __restrict__ qb = qhatb + (size_t)b * (QLEN * AD * 2);
    f32x4 sacc = (f32x4){0.f, 0.f, 0.f, 0.f};
    #pragma unroll
    for (int s = 0; s < 8; ++s) {
        const int tbyte = (tdoc * 512 + (s * 32 + lg * 8) * 2) ^ ((tdoc & 7) << 4);
        const bf16x8 ta = *(const bf16x8*)(Xb + tbyte);
        const int qbyte = (q * 512 + (s * 32 + lg * 8) * 2) ^ ((q & 7) << 4);
        const bf16x8 qv = *(const bf16x8*)(qb + qbyte);
        sacc = __builtin_amdgcn_mfma_f32_16x16x32_bf16(ta, qv, sacc, 0, 0, 0);
    }

    // ---- RBF: lane holds 4 docs (regs) x 1 q; accumulate in-lane over docs
    float kq[12];
    #pragma unroll
    for (int k = 0; k < 12; ++k) kq[k] = 0.f;
    #pragma unroll
    for (int reg = 0; reg < 4; ++reg) {
        const int doc = dtile * 16 + lg * 4 + reg;
        const float dnv = (toks[doc] == 0) ? 0.f
                                           : 1.f / (sqrtf(ssq[doc]) + 1e-9f);
        const float sv = sacc[reg] * dnv;
        kq[11] += sv;
        #pragma unroll
        for (int k = 0; k < NK; ++k) {
            const float t = sv - d_mus[k];
            kq[k] += __expf(d_coef[k] * t * t);
        }
    }
    #pragma unroll
    for (int m = 16; m <= 32; m <<= 1)
        #pragma unroll
        for (int k = 0; k < 12; ++k)
            kq[k] += __shfl_xor(kq[k], m, 64);
    if (lg == 0) {
        #pragma unroll
        for (int k = 0; k < 12; ++k)
            atomicAdd(&red[k * 32 + q], kq[k]);
    }
    __syncthreads();

    for (int i = tid; i < 384; i += 512) {
        const int k = i >> 5, qq = i & 31;
        if (k < NK) atomicAdd(&ksum[((size_t)b * NK + k) * QLEN + qq], red[i]);
        else        atomicAdd(&simsum[b * QLEN + qq], red[i]);
    }
}

// ---------------------------------------------------------------------------
__global__ __launch_bounds__(384) void knrm_final(
    const float* __restrict__ ksum,
    const float* __restrict__ simsum,
    const float* __restrict__ Wc, const float* __restrict__ bc,
    float* __restrict__ out)
{
    __shared__ float redq[NK][QLEN];
    __shared__ float res[NK];
    const int b = blockIdx.x;
    const int t = threadIdx.x;
    if (t < NK * QLEN) {
        const int k = t >> 5;
        const int q = t & 31;
        const float ms = simsum[b * QLEN + q];
        redq[k][q] = (ms != 0.0f)
            ? logf(ksum[((size_t)b * NK + k) * QLEN + q] + 1e-6f)
            : 0.0f;
    }
    __syncthreads();
    if (t < NK) {
        float s = 0.f;
        for (int q = 0; q < QLEN; ++q) s += redq[t][q];
        res[t] = s;
    }
    __syncthreads();
    if (t == 0) {
        float s = bc[0];
        for (int k = 0; k < NK; ++k) s += res[k] * Wc[k];
        out[b] = s;
    }
}

// ---------------------------------------------------------------------------
extern "C" void kernel_launch(void* const* d_in, const int* in_sizes, int n_in,
                              void* d_out, int out_size, void* d_ws, size_t ws_size,
                              hipStream_t stream)
{
    (void)in_sizes; (void)n_in; (void)out_size; (void)ws_size;
    const int*   qtok = (const int*)d_in[0];
    const int*   dtok = (const int*)d_in[1];
    const float* qent = (const float*)d_in[2];
    const float* dent = (const float*)d_in[3];
    const float* emb  = (const float*)d_in[4];
    const float* Wt   = (const float*)d_in[5];
    const float* bt   = (const float*)d_in[6];
    const float* We   = (const float*)d_in[7];
    const float* be   = (const float*)d_in[8];
    const float* Wc   = (const float*)d_in[9];
    const float* bc   = (const float*)d_in[10];
    float* out = (float*)d_out;

    char* ws = (char*)d_ws;
    char*   qhatb = ws;                                   // 1 MB bf16 swz
    __bf16* Wp    = (__bf16*)(ws + 1048576);              // 229376 B
    float*  bias  = (float*)(ws + 1048576 + 229376);      // 1 KB
    float*  ksum  = (float*)(ws + 1048576 + 229376 + 1024);        // 90112 B
    float*  simsum= (float*)(ws + 1048576 + 229376 + 1024 + 90112);// 8192 B

    hipMemsetAsync(ksum, 0, (size_t)(90112 + 8192), stream);

    knrm_wpack<<<dim3(56), dim3(256), 0, stream>>>(Wt, We, bt, be, Wp, bias);
    knrm_qtrans<<<dim3(B_), dim3(256), 0, stream>>>(
        qtok, qent, emb, Wt, bt, We, be, qhatb);
    knrm_doc<<<dim3(DLEN / 64, B_), dim3(512), 0, stream>>>(
        dtok, dent, emb, Wp, bias, qhatb, ksum, simsum);
    knrm_final<<<dim3(B_), dim3(384), 0, stream>>>(ksum, simsum, Wc, bc, out);
}